// Round 7
// baseline (556.071 us; speedup 1.0000x reference)
//
#include <hip/hip_runtime.h>
#include <stdint.h>

#define NN 50000
#define NE 800000
#define CAST_B 6250   // NN*128/4/256 exactly
#define CVTW_B 512    // 8*16384/256
#define EPB 8192      // edges per hist/scatter block
#define HIST_B 98     // ceil(NE/EPB)
#define NBK 196       // coarse buckets: dst>>8 (49999>>8 = 195)
#define NSLAB 7       // src slabs: src>>13 -> 0..6 (8192 nodes = 2MB bf16 each)
#define AGG_B 1564    // ceil(NN/32); 4 waves/block -> 24 waves/CU co-resident

typedef short short8 __attribute__((ext_vector_type(8)));
typedef float f32x4 __attribute__((ext_vector_type(4)));
typedef unsigned int uint;
typedef unsigned short ushort;

__device__ __forceinline__ uint rne_bf16(float f) {
    uint x = __float_as_uint(f);
    return (x + 0x7FFFu + ((x >> 16) & 1u)) >> 16;  // round-to-nearest-even
}
__device__ __forceinline__ float bf_lo(uint d) { return __uint_as_float(d << 16); }
__device__ __forceinline__ float bf_hi(uint d) { return __uint_as_float(d & 0xFFFF0000u); }

// int64 edge_index => int32 view is [lo,hi,lo,hi,...] with hi==0 (vals<50000).
// For int32 data these words are random node ids; P(all 4 zero) ~ 2e-19.
__device__ __forceinline__ int ei_is64(const int* __restrict__ ei) {
    return (ei[1] | ei[3] | ei[5] | ei[7]) == 0;
}

struct Ptrs8 { const float* p[8]; };

// -------- prep: x-cast | W-cast (fragment-major) | edge pack + coarse hist ---
// R0/R1 lesson: 800k global atomicAdds are serviced memory-side regardless of
// scope -> 2-level LDS-atomic bucket sort. R4 lesson (-53us): W cast into
// MFMA-FRAGMENT-MAJOR order so GEMM B loads are `base + lane*16B` coalesced.
__global__ __launch_bounds__(256) void k_prep(
    const float* __restrict__ x, ushort* __restrict__ xbf, Ptrs8 ps,
    ushort* __restrict__ wbf, const int* __restrict__ ei,
    uint* __restrict__ ebuf, int* __restrict__ hcnt) {
    __shared__ int hs[NBK];
    int b = blockIdx.x;
    if (b < CAST_B) {                       // cast x -> bf16 row-major
        int i = b * 256 + threadIdx.x;
        float4 v = ((const float4*)x)[i];
        uint2 o;
        o.x = rne_bf16(v.x) | (rne_bf16(v.y) << 16);
        o.y = rne_bf16(v.z) | (rne_bf16(v.w) << 16);
        ((uint2*)xbf)[i] = o;
    } else if (b < CAST_B + CVTW_B) {       // cast 8 W matrices, frag-major
        int idx = (b - CAST_B) * 256 + threadIdx.x;
        int m = idx >> 14;
        int o14 = idx & 16383;
        int k0i = (o14 >> 12) & 3;
        int t = (o14 >> 9) & 7;
        int lane6 = (o14 >> 3) & 63;
        int e = o14 & 7;
        int r = t * 16 + (lane6 & 15);
        int c = k0i * 32 + (lane6 >> 4) * 8 + e;
        wbf[idx] = (ushort)rne_bf16(ps.p[m][r * 128 + c]);
    } else {                                // pack edges + coarse hist
        int hb = b - CAST_B - CVTW_B;
        int t = threadIdx.x;
        for (int i = t; i < NBK; i += 256) hs[i] = 0;
        __syncthreads();
        int base = hb * EPB;
        int is64 = ei_is64(ei);
        for (int i = 0; i < EPB; i += 256) {
            int e = base + i + t;
            if (e < NE) {
                int sv = is64 ? ei[2 * e] : ei[e];
                int dv = is64 ? ei[2 * NE + 2 * e] : ei[NE + e];
                ebuf[e] = ((uint)dv << 16) | (uint)sv;
                atomicAdd(&hs[dv >> 8], 1);
            }
        }
        __syncthreads();
        for (int i = t; i < NBK; i += 256) hcnt[hb * NBK + i] = hs[i];
    }
}

// single block: bucket totals -> exclusive bases -> per-(block,bucket) offsets
__global__ __launch_bounds__(256) void k_scan1(const int* __restrict__ hcnt,
                                               int* __restrict__ hoff,
                                               int* __restrict__ bb) {
    __shared__ int s[256];
    int t = threadIdx.x;
    int tot = 0;
    if (t < NBK)
        for (int b = 0; b < HIST_B; b++) tot += hcnt[b * NBK + t];
    s[t] = tot;
    __syncthreads();
    for (int off = 1; off < 256; off <<= 1) {  // inclusive scan
        int v = s[t];
        int a = (t >= off) ? s[t - off] : 0;
        __syncthreads();
        s[t] = v + a;
        __syncthreads();
    }
    if (t < NBK) {
        int base = (t == 0) ? 0 : s[t - 1];  // exclusive
        bb[t] = base;
        int run = base;
        for (int b = 0; b < HIST_B; b++) {
            hoff[b * NBK + t] = run;
            run += hcnt[b * NBK + t];
        }
    }
    if (t == 0) bb[NBK] = NE;
}

// coarse scatter: LDS rank counters, writes land in ~170B runs per bucket
__global__ __launch_bounds__(256) void k_scatter1(const uint* __restrict__ ebuf,
                                                  const int* __restrict__ hoff,
                                                  uint* __restrict__ ebuf2) {
    __shared__ int pos[NBK];
    int hb = blockIdx.x, t = threadIdx.x;
    for (int i = t; i < NBK; i += 256) pos[i] = hoff[hb * NBK + i];
    __syncthreads();
    int base = hb * EPB;
    for (int i = 0; i < EPB; i += 256) {
        int e = base + i + t;
        if (e < NE) {
            uint pk = ebuf[e];
            int idx = atomicAdd(&pos[pk >> 24], 1);
            ebuf2[idx] = pk;
        }
    }
}

// per-bucket counting sort, R7: fine key = (dst&255)*8 | src_slab (2048 bins)
// -> rows are dst-contiguous AND slab-grouped within each row; emits
// row_ptr2[node*8+g] = start of node's slab-g segment. This is what enables
// temporal slab phasing in k_agg5 (L2-resident gathers).
__global__ __launch_bounds__(1024) void k_sort2(const uint* __restrict__ ebuf2,
                                                const int* __restrict__ bb,
                                                int* __restrict__ row_ptr2,
                                                ushort* __restrict__ col) {
    __shared__ int hist[2048];
    __shared__ int pos[2048];
    int k = blockIdx.x, t = threadIdx.x;
    int beg = bb[k], end = bb[k + 1];
    hist[t] = 0;
    hist[t + 1024] = 0;
    __syncthreads();
    for (int j = beg + t; j < end; j += 1024) {
        uint pk = ebuf2[j];
        int f = (((pk >> 16) & 255) << 3) | ((pk & 0xFFFFu) >> 13);
        atomicAdd(&hist[f], 1);
    }
    __syncthreads();
    // inclusive scan of each 1024-half, then offset the second half
    for (int off = 1; off < 1024; off <<= 1) {
        int v0 = hist[t], v1 = hist[1024 + t];
        int a0 = (t >= off) ? hist[t - off] : 0;
        int a1 = (t >= off) ? hist[1024 + t - off] : 0;
        __syncthreads();
        hist[t] = v0 + a0;
        hist[1024 + t] = v1 + a1;
        __syncthreads();
    }
    int tot0 = hist[1023];
    __syncthreads();
    hist[1024 + t] += tot0;
    __syncthreads();
    for (int b = t; b < 2048; b += 1024) {
        int ex = (b == 0) ? 0 : hist[b - 1];  // exclusive
        pos[b] = beg + ex;
        int node = k * 256 + (b >> 3);
        if (node < NN) row_ptr2[node * 8 + (b & 7)] = beg + ex;
    }
    if (k == 0 && t == 0) row_ptr2[NN * 8] = NE;
    __syncthreads();
    for (int j = beg + t; j < end; j += 1024) {
        uint pk = ebuf2[j];
        int f = (((pk >> 16) & 255) << 3) | ((pk & 0xFFFFu) >> 13);
        int idx = atomicAdd(&pos[f], 1);
        col[idx] = (ushort)(pk & 0xFFFFu);
    }
}

// -------- slab-phased mean aggregation (R7) ----------------------------------
// R5/R6 lesson: the gather floor (~40us/layer) is L2-miss service, NOT wave
// concurrency (25%->54% occupancy moved dur 2%). Fix the hit rate: all
// co-resident waves gather from ONE 2MB src-slab at a time. Rows are
// slab-grouped (k_sort2); accumulators stay in registers across slabs;
// __syncthreads per slab keeps the block in phase; cross-block alignment from
// full co-residency (1564 blk x 4 waves = 24 waves/CU) + CLT (block work/slab
// = sum of 32 Poisson degrees, sigma ~3%). Per-edge structure identical to
// the measured-best agg3 (full 256B rows, 8-deep masked pipeline; clamped
// duplicate loads are L1 hits = no L2 traffic). R2 lesson stands: never
// feature-split the gathers.
__global__ __launch_bounds__(256, 6) void k_agg5(
    const ushort* __restrict__ h, const int* __restrict__ rp2,
    const ushort* __restrict__ col, ushort* __restrict__ mean) {
    const int wid = threadIdx.x >> 6;
    const int lane = threadIdx.x & 63;
    const int n0 = blockIdx.x * 32 + wid * 8;
    const uint* hp = (const uint*)h;  // row = 64 uints (128 bf16)
    float a0[8], a1[8];
    int dg[8];
#pragma unroll
    for (int ni = 0; ni < 8; ni++) { a0[ni] = 0.f; a1[ni] = 0.f; dg[ni] = 0; }

    for (int g = 0; g < NSLAB; g++) {
        int len[8], cc[8];
#pragma unroll
        for (int ni = 0; ni < 8; ni++) {
            int node = n0 + ni;
            int beg = 0, end = 0;
            if (node < NN) {
                int2 be = *(const int2*)&rp2[node * 8 + g];
                beg = be.x; end = be.y;
            }
            int L = end - beg;
            len[ni] = L;
            dg[ni] += L;
            cc[ni] = (int)col[beg + min(lane, max(L - 1, 0))];
        }
        int ml = 0;
#pragma unroll
        for (int ni = 0; ni < 8; ni++) ml = max(ml, len[ni]);
        ml = min(ml, 64);
        for (int j = 0; j < ml; j++) {
            uint v[8];
#pragma unroll
            for (int ni = 0; ni < 8; ni++) {
                int s = __shfl(cc[ni], min(j, max(len[ni] - 1, 0)));
                v[ni] = hp[(size_t)s * 64 + lane];  // coalesced 256B row
            }
#pragma unroll
            for (int ni = 0; ni < 8; ni++) {
                float m = (j < len[ni]) ? 1.f : 0.f;
                a0[ni] = fmaf(m, bf_lo(v[ni]), a0[ni]);
                a1[ni] = fmaf(m, bf_hi(v[ni]), a1[ni]);
            }
        }
        // rare tail: per-(node,slab) segment longer than 64 (Poisson(2.3))
#pragma unroll
        for (int ni = 0; ni < 8; ni++) {
            if (__builtin_expect(len[ni] > 64, 0)) {
                int node = n0 + ni;
                int2 be = *(const int2*)&rp2[node * 8 + g];
                for (int b = be.x + 64; b < be.y; b += 64) {
                    int n = min(64, be.y - b);
                    int c = (int)col[b + min(lane, n - 1)];
                    for (int j = 0; j < n; j++) {
                        int s = __shfl(c, j);
                        uint v = hp[(size_t)s * 64 + lane];
                        a0[ni] += bf_lo(v);
                        a1[ni] += bf_hi(v);
                    }
                }
            }
        }
        __syncthreads();  // keep the block's waves on the same slab
    }
#pragma unroll
    for (int ni = 0; ni < 8; ni++) {
        int node = n0 + ni;
        if (node < NN) {
            float r = 1.0f / (float)max(dg[ni], 1);
            ((uint*)mean)[(size_t)node * 64 + lane] =
                rne_bf16(a0[ni] * r) | (rne_bf16(a1[ni] * r) << 16);
        }
    }
}

// ------- MFMA GEMM: out = mean@Wl^T + h@Wr^T + b (+ReLU), 32 rows/wave -------
// R4 (-53us): B operand (W) is fragment-major -> every B load is a coalesced
// `base + lane*16B` 1KB wave load; each B fragment feeds 2 MFMAs.
__global__ __launch_bounds__(256) void k_gemm_mfma(
    const ushort* __restrict__ Am, const ushort* __restrict__ Ah,
    const ushort* __restrict__ Wlb, const ushort* __restrict__ Wrb,
    const float* __restrict__ bias, float* __restrict__ outf,
    ushort* __restrict__ outb, int relu) {
    const int lane = threadIdx.x & 63;
    const int wave = threadIdx.x >> 6;
    const int l15 = lane & 15;
    const int quad = lane >> 4;
    const int m0 = blockIdx.x * 128 + wave * 32;

    f32x4 acc[2][8];
#pragma unroll
    for (int s = 0; s < 2; s++)
#pragma unroll
        for (int t = 0; t < 8; t++) acc[s][t] = (f32x4){0.f, 0.f, 0.f, 0.f};

    int ar0 = min(m0 + l15, NN - 1);       // clamp loads; stores guarded below
    int ar1 = min(m0 + 16 + l15, NN - 1);
    const ushort* A0m = Am + (size_t)ar0 * 128 + quad * 8;
    const ushort* A1m = Am + (size_t)ar1 * 128 + quad * 8;
    const ushort* A0h = Ah + (size_t)ar0 * 128 + quad * 8;
    const ushort* A1h = Ah + (size_t)ar1 * 128 + quad * 8;

#pragma unroll
    for (int half = 0; half < 2; half++) {
        const ushort* W = half ? Wrb : Wlb;
        const ushort* A0 = half ? A0h : A0m;
        const ushort* A1 = half ? A1h : A1m;
#pragma unroll
        for (int k0 = 0; k0 < 128; k0 += 32) {
            short8 a0 = *(const short8*)(A0 + k0);
            short8 a1 = *(const short8*)(A1 + k0);
            const ushort* Wk = W + ((k0 >> 5) * 8) * 512 + lane * 8;
#pragma unroll
            for (int t = 0; t < 8; t++) {
                short8 b = *(const short8*)(Wk + t * 512);
                acc[0][t] = __builtin_amdgcn_mfma_f32_16x16x32_bf16(a0, b, acc[0][t], 0, 0, 0);
                acc[1][t] = __builtin_amdgcn_mfma_f32_16x16x32_bf16(a1, b, acc[1][t], 0, 0, 0);
            }
        }
    }

    float bb[8];
#pragma unroll
    for (int t = 0; t < 8; t++) bb[t] = bias[t * 16 + l15];

#pragma unroll
    for (int s = 0; s < 2; s++) {
#pragma unroll
        for (int r = 0; r < 4; r++) {
            int row = m0 + s * 16 + quad * 4 + r;  // C/D: row = quad*4 + reg
            if (row < NN) {
#pragma unroll
                for (int t = 0; t < 8; t++) {
                    float v = acc[s][t][r] + bb[t];
                    if (relu) v = fmaxf(v, 0.f);
                    if (outb) outb[(size_t)row * 128 + t * 16 + l15] = (ushort)rne_bf16(v);
                    else outf[(size_t)row * 128 + t * 16 + l15] = v;
                }
            }
        }
    }
}

extern "C" void kernel_launch(void* const* d_in, const int* in_sizes, int n_in,
                              void* d_out, int out_size, void* d_ws, size_t ws_size,
                              hipStream_t stream) {
    const float* x = (const float*)d_in[0];
    const int* ei = (const int*)d_in[1];
    const float* Wl[4] = {(const float*)d_in[2], (const float*)d_in[5],
                          (const float*)d_in[8], (const float*)d_in[11]};
    const float* bl[4] = {(const float*)d_in[3], (const float*)d_in[6],
                          (const float*)d_in[9], (const float*)d_in[12]};
    const float* Wr[4] = {(const float*)d_in[4], (const float*)d_in[7],
                          (const float*)d_in[10], (const float*)d_in[13]};
    float* out = (float*)d_out;

    char* p = (char*)d_ws;
    auto take = [&](size_t bytes) -> char* {
        char* r = p;
        p += (bytes + 255) & ~(size_t)255;
        return r;
    };
    uint* ebuf = (uint*)take((size_t)NE * 4);
    uint* ebuf2 = (uint*)take((size_t)NE * 4);
    int* hcnt = (int*)take((size_t)HIST_B * NBK * 4);
    int* hoff = (int*)take((size_t)HIST_B * NBK * 4);
    int* bb = (int*)take((NBK + 1) * 4);
    int* row_ptr2 = (int*)take(((size_t)NN * 8 + 8) * 4);
    ushort* col = (ushort*)take((size_t)NE * 2 + 256);  // +pad
    ushort* xbf = (ushort*)take((size_t)NN * 128 * 2);
    ushort* h1 = (ushort*)take((size_t)NN * 128 * 2);
    ushort* h2 = (ushort*)take((size_t)NN * 128 * 2);
    ushort* meanbf = (ushort*)take((size_t)NN * 128 * 2);
    ushort* wbf = (ushort*)take(8 * 16384 * 2);

    Ptrs8 ps;
    ps.p[0] = Wl[0]; ps.p[1] = Wr[0]; ps.p[2] = Wl[1]; ps.p[3] = Wr[1];
    ps.p[4] = Wl[2]; ps.p[5] = Wr[2]; ps.p[6] = Wl[3]; ps.p[7] = Wr[3];

    // CSR via 2-level bucket sort: no global atomics, no memset, no fill.
    k_prep<<<CAST_B + CVTW_B + HIST_B, 256, 0, stream>>>(x, xbf, ps, wbf, ei,
                                                         ebuf, hcnt);
    k_scan1<<<1, 256, 0, stream>>>(hcnt, hoff, bb);
    k_scatter1<<<HIST_B, 256, 0, stream>>>(ebuf, hoff, ebuf2);
    k_sort2<<<NBK, 1024, 0, stream>>>(ebuf2, bb, row_ptr2, col);

    const ushort* h = xbf;
    ushort* houts[4] = {h1, h2, h1, nullptr};  // final layer -> fp32 d_out
    for (int l = 0; l < 4; l++) {
        k_agg5<<<AGG_B, 256, 0, stream>>>(h, row_ptr2, col, meanbf);
        k_gemm_mfma<<<(NN + 127) / 128, 256, 0, stream>>>(
            meanbf, h, wbf + (size_t)(2 * l) * 16384,
            wbf + (size_t)(2 * l + 1) * 16384, bl[l], out, houts[l],
            l == 0 ? 1 : 0);
        h = houts[l];
    }
}

// Round 8
// 357.328 us; speedup vs baseline: 1.5562x; 1.5562x over previous
//
#include <hip/hip_runtime.h>
#include <stdint.h>

#define NN 50000
#define NE 800000
#define CAST_B 6250   // NN*128/4/256 exactly
#define CVTW_B 512    // 8*16384/256
#define EPB 8192      // edges per hist/scatter block
#define HIST_B 98     // ceil(NE/EPB)
#define NBK 196       // coarse buckets: dst>>8 (49999>>8 = 195)

typedef short short8 __attribute__((ext_vector_type(8)));
typedef float f32x4 __attribute__((ext_vector_type(4)));
typedef unsigned int uint;
typedef unsigned short ushort;

__device__ __forceinline__ uint rne_bf16(float f) {
    uint x = __float_as_uint(f);
    return (x + 0x7FFFu + ((x >> 16) & 1u)) >> 16;  // round-to-nearest-even
}
__device__ __forceinline__ float bf_lo(uint d) { return __uint_as_float(d << 16); }
__device__ __forceinline__ float bf_hi(uint d) { return __uint_as_float(d & 0xFFFF0000u); }

// int64 edge_index => int32 view is [lo,hi,lo,hi,...] with hi==0 (vals<50000).
// For int32 data these words are random node ids; P(all 4 zero) ~ 2e-19.
__device__ __forceinline__ int ei_is64(const int* __restrict__ ei) {
    return (ei[1] | ei[3] | ei[5] | ei[7]) == 0;
}

struct Ptrs8 { const float* p[8]; };

// -------- prep: x-cast | W-cast (fragment-major) | edge pack + coarse hist ---
// R0/R1 lesson: 800k global atomicAdds are serviced memory-side (~18 Gops/s,
// 25.6MB write-through) regardless of scope -> 2-level LDS-atomic bucket sort.
// R4 lesson (-53us): W cast into MFMA-FRAGMENT-MAJOR order so GEMM B loads are
// `base + lane*16B` coalesced 1KB wave loads. Within matrix m:
// idx = ((k0i*8 + t)*64 + lane)*8+e holds W[r=t*16+(lane&15)][c=k0i*32+(lane>>4)*8+e].
__global__ __launch_bounds__(256) void k_prep(
    const float* __restrict__ x, ushort* __restrict__ xbf, Ptrs8 ps,
    ushort* __restrict__ wbf, const int* __restrict__ ei,
    uint* __restrict__ ebuf, int* __restrict__ hcnt) {
    __shared__ int hs[NBK];
    int b = blockIdx.x;
    if (b < CAST_B) {                       // cast x -> bf16 row-major
        int i = b * 256 + threadIdx.x;
        float4 v = ((const float4*)x)[i];
        uint2 o;
        o.x = rne_bf16(v.x) | (rne_bf16(v.y) << 16);
        o.y = rne_bf16(v.z) | (rne_bf16(v.w) << 16);
        ((uint2*)xbf)[i] = o;
    } else if (b < CAST_B + CVTW_B) {       // cast 8 W matrices, frag-major
        int idx = (b - CAST_B) * 256 + threadIdx.x;
        int m = idx >> 14;
        int o14 = idx & 16383;
        int k0i = (o14 >> 12) & 3;
        int t = (o14 >> 9) & 7;
        int lane6 = (o14 >> 3) & 63;
        int e = o14 & 7;
        int r = t * 16 + (lane6 & 15);
        int c = k0i * 32 + (lane6 >> 4) * 8 + e;
        wbf[idx] = (ushort)rne_bf16(ps.p[m][r * 128 + c]);
    } else {                                // pack edges + coarse hist
        int hb = b - CAST_B - CVTW_B;
        int t = threadIdx.x;
        for (int i = t; i < NBK; i += 256) hs[i] = 0;
        __syncthreads();
        int base = hb * EPB;
        int is64 = ei_is64(ei);
        for (int i = 0; i < EPB; i += 256) {
            int e = base + i + t;
            if (e < NE) {
                int sv = is64 ? ei[2 * e] : ei[e];
                int dv = is64 ? ei[2 * NE + 2 * e] : ei[NE + e];
                ebuf[e] = ((uint)dv << 16) | (uint)sv;
                atomicAdd(&hs[dv >> 8], 1);
            }
        }
        __syncthreads();
        for (int i = t; i < NBK; i += 256) hcnt[hb * NBK + i] = hs[i];
    }
}

// coarse scatter (R8: scan folded in). Each block redundantly recomputes the
// global bucket bases + its own per-block offsets from hcnt (76KB L2-hot reads,
// ~20k adds) -- removes the separate k_scan1 dispatch + stream drain. Block 0
// also publishes bb[] for k_sort2 (which runs after this kernel completes).
__global__ __launch_bounds__(256) void k_scatter1(const uint* __restrict__ ebuf,
                                                  const int* __restrict__ hcnt,
                                                  int* __restrict__ bb,
                                                  uint* __restrict__ ebuf2) {
    __shared__ int s[256];
    __shared__ int pos[NBK];
    int hb = blockIdx.x, t = threadIdx.x;
    // tot[t] = column sum; partial[t] = sum over blocks < hb  (one fused pass)
    int tot = 0, partial = 0;
    if (t < NBK) {
        for (int b = 0; b < HIST_B; b++) {
            int v = hcnt[b * NBK + t];
            tot += v;
            if (b < hb) partial += v;
        }
    }
    s[t] = tot;
    __syncthreads();
    for (int off = 1; off < 256; off <<= 1) {  // inclusive scan of totals
        int v = s[t];
        int a = (t >= off) ? s[t - off] : 0;
        __syncthreads();
        s[t] = v + a;
        __syncthreads();
    }
    if (t < NBK) {
        int base = (t == 0) ? 0 : s[t - 1];  // exclusive bucket base
        pos[t] = base + partial;
        if (hb == 0) bb[t] = base;
    }
    if (hb == 0 && t == 0) bb[NBK] = NE;
    __syncthreads();
    int base = hb * EPB;
    for (int i = 0; i < EPB; i += 256) {
        int e = base + i + t;
        if (e < NE) {
            uint pk = ebuf[e];
            int idx = atomicAdd(&pos[pk >> 24], 1);
            ebuf2[idx] = pk;
        }
    }
}

// per-bucket counting sort: one block per 256-node bucket (~4k edges), two
// passes over its global range; emits col (src) and row_ptr directly.
__global__ __launch_bounds__(1024) void k_sort2(const uint* __restrict__ ebuf2,
                                                const int* __restrict__ bb,
                                                int* __restrict__ row_ptr,
                                                ushort* __restrict__ col) {
    __shared__ int hist[256];
    __shared__ int pos[256];
    int k = blockIdx.x, t = threadIdx.x;
    int beg = bb[k], end = bb[k + 1];
    if (t < 256) hist[t] = 0;
    __syncthreads();
    for (int j = beg + t; j < end; j += 1024)
        atomicAdd(&hist[(ebuf2[j] >> 16) & 255], 1);
    __syncthreads();
    for (int off = 1; off < 256; off <<= 1) {  // inclusive scan (1024-thr safe)
        int v = 0;
        if (t < 256) { v = hist[t]; if (t >= off) v += hist[t - off]; }
        __syncthreads();
        if (t < 256) hist[t] = v;
        __syncthreads();
    }
    if (t < 256) {
        int ex = (t == 0) ? 0 : hist[t - 1];
        pos[t] = beg + ex;
        int node = k * 256 + t;
        if (node < NN) row_ptr[node] = beg + ex;
    }
    if (k == 0 && t == 0) row_ptr[NN] = NE;
    __syncthreads();
    for (int j = beg + t; j < end; j += 1024) {
        uint pk = ebuf2[j];
        int idx = atomicAdd(&pos[(pk >> 16) & 255], 1);
        col[idx] = (ushort)(pk & 0xFFFFu);
    }
}

// ---------------- mean aggregation (measured-best structure) -----------------
// One wave per node; lane = bf16 pair. One col load covers 64 edges; row
// gathers are independent 256B coalesced wave loads. ~40us/layer = ~5 TB/s
// effective on 205MB of random-row gathers (~80% of streaming ceiling).
// Floor bracketed by 5 falsified variants: R2 feature-split (2x worse, per-wave
// overhead), R5/R6 fusion (neutral; occupancy 25->54% moved dur 2% => NOT
// concurrency-bound), R7 slab-phasing (2x worse, masked-load waste on 2.3-edge
// segments). Do not restructure again without new counter evidence.
__global__ __launch_bounds__(256) void k_agg3(const ushort* __restrict__ h,
                                              const int* __restrict__ row_ptr,
                                              const ushort* __restrict__ col,
                                              ushort* __restrict__ mean) {
    int node = blockIdx.x * 4 + (threadIdx.x >> 6);
    if (node >= NN) return;
    int lane = threadIdx.x & 63;
    int beg = row_ptr[node], end = row_ptr[node + 1];
    const uint* hp = (const uint*)h;  // row = 64 uints (128 bf16)
    float a0 = 0.f, a1 = 0.f;
    for (int b = beg; b < end; b += 64) {   // one iteration for deg <= 64
        int n = min(64, end - b);
        int c = (int)col[b + min(lane, n - 1)];
        for (int j0 = 0; j0 < n; j0 += 8) {
#pragma unroll
            for (int j = 0; j < 8; j++) {
                int jj = j0 + j;                     // wave-uniform
                int s = __shfl(c, min(jj, n - 1));   // uniform broadcast
                uint v = hp[s * 64 + lane];          // coalesced 256B row
                float m = (jj < n) ? 1.f : 0.f;
                a0 = fmaf(m, bf_lo(v), a0);
                a1 = fmaf(m, bf_hi(v), a1);
            }
        }
    }
    float r = 1.0f / (float)max(end - beg, 1);  // deg from row_ptr: free rinv
    ((uint*)mean)[node * 64 + lane] = rne_bf16(a0 * r) | (rne_bf16(a1 * r) << 16);
}

// ------- MFMA GEMM: out = mean@Wl^T + h@Wr^T + b (+ReLU), 32 rows/wave -------
// R4 (-53us): B operand (W) is fragment-major (see k_prep) -> every B load is
// a coalesced `base + lane*16B` 1KB wave load; each B fragment feeds 2 MFMAs
// (two 16-row A sets), halving B-load instruction count and B traffic.
__global__ __launch_bounds__(256) void k_gemm_mfma(
    const ushort* __restrict__ Am, const ushort* __restrict__ Ah,
    const ushort* __restrict__ Wlb, const ushort* __restrict__ Wrb,
    const float* __restrict__ bias, float* __restrict__ outf,
    ushort* __restrict__ outb, int relu) {
    const int lane = threadIdx.x & 63;
    const int wave = threadIdx.x >> 6;
    const int l15 = lane & 15;
    const int quad = lane >> 4;
    const int m0 = blockIdx.x * 128 + wave * 32;

    f32x4 acc[2][8];
#pragma unroll
    for (int s = 0; s < 2; s++)
#pragma unroll
        for (int t = 0; t < 8; t++) acc[s][t] = (f32x4){0.f, 0.f, 0.f, 0.f};

    int ar0 = min(m0 + l15, NN - 1);       // clamp loads; stores guarded below
    int ar1 = min(m0 + 16 + l15, NN - 1);
    const ushort* A0m = Am + (size_t)ar0 * 128 + quad * 8;
    const ushort* A1m = Am + (size_t)ar1 * 128 + quad * 8;
    const ushort* A0h = Ah + (size_t)ar0 * 128 + quad * 8;
    const ushort* A1h = Ah + (size_t)ar1 * 128 + quad * 8;

#pragma unroll
    for (int half = 0; half < 2; half++) {
        const ushort* W = half ? Wrb : Wlb;
        const ushort* A0 = half ? A0h : A0m;
        const ushort* A1 = half ? A1h : A1m;
#pragma unroll
        for (int k0 = 0; k0 < 128; k0 += 32) {
            short8 a0 = *(const short8*)(A0 + k0);
            short8 a1 = *(const short8*)(A1 + k0);
            const ushort* Wk = W + ((k0 >> 5) * 8) * 512 + lane * 8;
#pragma unroll
            for (int t = 0; t < 8; t++) {
                short8 b = *(const short8*)(Wk + t * 512);
                acc[0][t] = __builtin_amdgcn_mfma_f32_16x16x32_bf16(a0, b, acc[0][t], 0, 0, 0);
                acc[1][t] = __builtin_amdgcn_mfma_f32_16x16x32_bf16(a1, b, acc[1][t], 0, 0, 0);
            }
        }
    }

    float bb[8];
#pragma unroll
    for (int t = 0; t < 8; t++) bb[t] = bias[t * 16 + l15];

#pragma unroll
    for (int s = 0; s < 2; s++) {
#pragma unroll
        for (int r = 0; r < 4; r++) {
            int row = m0 + s * 16 + quad * 4 + r;  // C/D: row = quad*4 + reg
            if (row < NN) {
#pragma unroll
                for (int t = 0; t < 8; t++) {
                    float v = acc[s][t][r] + bb[t];
                    if (relu) v = fmaxf(v, 0.f);
                    if (outb) outb[(size_t)row * 128 + t * 16 + l15] = (ushort)rne_bf16(v);
                    else outf[(size_t)row * 128 + t * 16 + l15] = v;
                }
            }
        }
    }
}

extern "C" void kernel_launch(void* const* d_in, const int* in_sizes, int n_in,
                              void* d_out, int out_size, void* d_ws, size_t ws_size,
                              hipStream_t stream) {
    const float* x = (const float*)d_in[0];
    const int* ei = (const int*)d_in[1];
    const float* Wl[4] = {(const float*)d_in[2], (const float*)d_in[5],
                          (const float*)d_in[8], (const float*)d_in[11]};
    const float* bl[4] = {(const float*)d_in[3], (const float*)d_in[6],
                          (const float*)d_in[9], (const float*)d_in[12]};
    const float* Wr[4] = {(const float*)d_in[4], (const float*)d_in[7],
                          (const float*)d_in[10], (const float*)d_in[13]};
    float* out = (float*)d_out;

    char* p = (char*)d_ws;
    auto take = [&](size_t bytes) -> char* {
        char* r = p;
        p += (bytes + 255) & ~(size_t)255;
        return r;
    };
    uint* ebuf = (uint*)take((size_t)NE * 4);
    uint* ebuf2 = (uint*)take((size_t)NE * 4);
    int* hcnt = (int*)take((size_t)HIST_B * NBK * 4);
    int* bb = (int*)take((NBK + 1) * 4);
    int* row_ptr = (int*)take((NN + 1) * 4);
    ushort* col = (ushort*)take((size_t)NE * 2 + 256);  // +pad
    ushort* xbf = (ushort*)take((size_t)NN * 128 * 2);
    ushort* h1 = (ushort*)take((size_t)NN * 128 * 2);
    ushort* h2 = (ushort*)take((size_t)NN * 128 * 2);
    ushort* meanbf = (ushort*)take((size_t)NN * 128 * 2);
    ushort* wbf = (ushort*)take(8 * 16384 * 2);

    Ptrs8 ps;
    ps.p[0] = Wl[0]; ps.p[1] = Wr[0]; ps.p[2] = Wl[1]; ps.p[3] = Wr[1];
    ps.p[4] = Wl[2]; ps.p[5] = Wr[2]; ps.p[6] = Wl[3]; ps.p[7] = Wr[3];

    // CSR via 2-level bucket sort: no global atomics, no memset, no fill.
    // R8: scan folded into scatter (one fewer dispatch + drain).
    k_prep<<<CAST_B + CVTW_B + HIST_B, 256, 0, stream>>>(x, xbf, ps, wbf, ei,
                                                         ebuf, hcnt);
    k_scatter1<<<HIST_B, 256, 0, stream>>>(ebuf, hcnt, bb, ebuf2);
    k_sort2<<<NBK, 1024, 0, stream>>>(ebuf2, bb, row_ptr, col);

    const ushort* h = xbf;
    ushort* houts[4] = {h1, h2, h1, nullptr};  // final layer -> fp32 d_out
    for (int l = 0; l < 4; l++) {
        k_agg3<<<(NN + 3) / 4, 256, 0, stream>>>(h, row_ptr, col, meanbf);
        k_gemm_mfma<<<(NN + 127) / 128, 256, 0, stream>>>(
            meanbf, h, wbf + (size_t)(2 * l) * 16384,
            wbf + (size_t)(2 * l + 1) * 16384, bl[l], out, houts[l],
            l == 0 ? 1 : 0);
        h = houts[l];
    }
}